// Round 1
// baseline (3036.801 us; speedup 1.0000x reference)
//
#include <hip/hip_runtime.h>
#include <stdint.h>

#define B_ 64
#define D_ 1024
#define H_ 1024
#define V_ 32000
#define T_ 20

typedef __attribute__((ext_vector_type(8))) __bf16 bf16x8;
typedef __attribute__((ext_vector_type(4))) float f32x4;

// ---------------------------------------------------------------- helpers
__device__ __forceinline__ uint32_t ord_of_float(float x) {
    uint32_t u = __float_as_uint(x);
    return (u & 0x80000000u) ? ~u : (u | 0x80000000u);
}

__device__ __forceinline__ unsigned long long shfl_xor_u64(unsigned long long x, int m) {
    return (unsigned long long)__shfl_xor((long long)x, m, 64);
}

// round-to-nearest-even fp32 -> bf16 split: f ~= hi + lo (each bf16)
__device__ __forceinline__ void split_bf16(float f, unsigned short* hi, unsigned short* lo) {
    uint32_t u = __float_as_uint(f);
    uint32_t rh = (u + 0x7FFFu + ((u >> 16) & 1u)) >> 16;
    *hi = (unsigned short)rh;
    float fl = f - __uint_as_float(rh << 16);
    uint32_t ul = __float_as_uint(fl);
    uint32_t rl = (ul + 0x7FFFu + ((ul >> 16) & 1u)) >> 16;
    *lo = (unsigned short)rl;
}

// ---------------------------------------------------------------- init hidden
// h0[b][j] = dot(latent[b,:], Wp[j,:]) + bp[j].  One wave per output.
__global__ __launch_bounds__(256) void k_init_hidden(
    const float* __restrict__ latent, const float* __restrict__ Wp,
    const float* __restrict__ bp, float* __restrict__ h0)
{
    int gw = (blockIdx.x * 256 + threadIdx.x) >> 6;  // global wave id
    int lane = threadIdx.x & 63;
    int j = gw >> 6;      // 16 consecutive blocks share j -> L2 reuse of Wp row
    int b = gw & 63;
    const float4* a4 = (const float4*)(latent + b * D_);
    const float4* w4 = (const float4*)(Wp + (size_t)j * D_);
    float s = 0.f;
#pragma unroll
    for (int i = 0; i < 4; i++) {
        float4 a = a4[lane + 64 * i];
        float4 w = w4[lane + 64 * i];
        s += a.x * w.x + a.y * w.y + a.z * w.z + a.w * w.w;
    }
#pragma unroll
    for (int off = 32; off; off >>= 1) s += __shfl_down(s, off, 64);
    if (lane == 0) h0[b * H_ + j] = s + bp[j];
}

// ---------------------------------------------------------------- GRU gates (fp32)
// Block: all 64 b x 4 j.  lane = b, wave = local j.  x/h chunks staged in LDS
// (stride 33 -> conflict-free scalar reads); weights read wave-uniformly
// (scalar-load path).  Writes hnext[b][j] (double-buffered vs hprev).
__global__ __launch_bounds__(256) void k_gru_gates(
    const float* __restrict__ emb, const int* __restrict__ tok, int use_sos,
    const float* __restrict__ Wih, const float* __restrict__ bih,
    const float* __restrict__ Whh, const float* __restrict__ bhh,
    const float* __restrict__ hprev, float* __restrict__ hnext)
{
    __shared__ float xs[64 * 33];
    __shared__ float hs[64 * 33];
    int tid = threadIdx.x;
    int lane = tid & 63;
    int wv = __builtin_amdgcn_readfirstlane(tid >> 6);
    int j = blockIdx.x * 4 + wv;

    int srow = tid >> 2;         // staging row (b)
    int scol = (tid & 3) * 8;    // staging col
    int xrow = use_sos ? 0 : tok[srow];
    const float* xsrc = emb + (size_t)xrow * H_ + scol;
    const float* hsrc = hprev + srow * H_ + scol;
    float* xd = xs + srow * 33 + scol;
    float* hd = hs + srow * 33 + scol;

    const float* wr = Wih + (size_t)j * H_;
    const float* wz = Wih + (size_t)(H_ + j) * H_;
    const float* wn = Wih + (size_t)(2 * H_ + j) * H_;
    const float* ur = Whh + (size_t)j * H_;
    const float* uz = Whh + (size_t)(H_ + j) * H_;
    const float* un = Whh + (size_t)(2 * H_ + j) * H_;

    float air = 0.f, aiz = 0.f, ain = 0.f, ahr = 0.f, ahz = 0.f, ahn = 0.f;

    for (int kc = 0; kc < H_; kc += 32) {
        float4 x0 = *(const float4*)(xsrc + kc);
        float4 x1 = *(const float4*)(xsrc + kc + 4);
        float4 g0 = *(const float4*)(hsrc + kc);
        float4 g1 = *(const float4*)(hsrc + kc + 4);
        __syncthreads();
        xd[0] = x0.x; xd[1] = x0.y; xd[2] = x0.z; xd[3] = x0.w;
        xd[4] = x1.x; xd[5] = x1.y; xd[6] = x1.z; xd[7] = x1.w;
        hd[0] = g0.x; hd[1] = g0.y; hd[2] = g0.z; hd[3] = g0.w;
        hd[4] = g1.x; hd[5] = g1.y; hd[6] = g1.z; hd[7] = g1.w;
        __syncthreads();
#pragma unroll
        for (int k = 0; k < 32; k++) {
            float xk = xs[lane * 33 + k];
            float hk = hs[lane * 33 + k];
            air = fmaf(xk, wr[kc + k], air);
            aiz = fmaf(xk, wz[kc + k], aiz);
            ain = fmaf(xk, wn[kc + k], ain);
            ahr = fmaf(hk, ur[kc + k], ahr);
            ahz = fmaf(hk, uz[kc + k], ahz);
            ahn = fmaf(hk, un[kc + k], ahn);
        }
    }
    float ir = air + bih[j],          hr = ahr + bhh[j];
    float iz = aiz + bih[H_ + j],     hz = ahz + bhh[H_ + j];
    float in_ = ain + bih[2 * H_ + j], hn = ahn + bhh[2 * H_ + j];
    float r = 1.f / (1.f + expf(-(ir + hr)));
    float z = 1.f / (1.f + expf(-(iz + hz)));
    float n = tanhf(in_ + r * hn);
    float hp = hprev[lane * H_ + j];
    hnext[lane * H_ + j] = (1.f - z) * n + z * hp;
}

// ---------------------------------------------------------------- logits + argmax
// Split-precision bf16 MFMA GEMM: logits = h @ Wout^T + bout, computed as
// hi*hi + lo*hi + hi*lo (error ~4e-7 << top1-top2 gap).  Block: 64 b x 64 v.
// Epilogue reduces to per-b packed (logit,v) max over the block's v-tile and
// writes partials[b][block] (no atomics).
#define LSTRIDE 72  // 64 + 8 pad (keeps 16B alignment, 2-way-max conflicts)

__global__ __launch_bounds__(256) void k_logits_argmax(
    const float* __restrict__ hcur, const float* __restrict__ Wout,
    const float* __restrict__ bout, unsigned long long* __restrict__ partials,
    int nblk)
{
    __shared__ unsigned short Ahi[64 * LSTRIDE], Alo[64 * LSTRIDE];
    __shared__ unsigned short Bhi[64 * LSTRIDE], Blo[64 * LSTRIDE];
    int tid = threadIdx.x;
    int lane = tid & 63;
    int wv = tid >> 6;
    int vbase = blockIdx.x * 64;

    int srow = tid >> 2;
    int scol = (tid & 3) * 16;
    const float* asrc = hcur + srow * H_ + scol;
    const float* bsrc = Wout + (size_t)(vbase + srow) * H_ + scol;
    unsigned short* ahd = Ahi + srow * LSTRIDE + scol;
    unsigned short* ald = Alo + srow * LSTRIDE + scol;
    unsigned short* bhd = Bhi + srow * LSTRIDE + scol;
    unsigned short* bld = Blo + srow * LSTRIDE + scol;

    f32x4 acc[4];
#pragma unroll
    for (int i = 0; i < 4; i++) acc[i] = (f32x4){0.f, 0.f, 0.f, 0.f};

    int arow = wv * 16 + (lane & 15);
    int koff = (lane >> 4) * 8;

    for (int kc = 0; kc < H_; kc += 64) {
        float4 av[4], bv[4];
#pragma unroll
        for (int i = 0; i < 4; i++) {
            av[i] = *(const float4*)(asrc + kc + 4 * i);
            bv[i] = *(const float4*)(bsrc + kc + 4 * i);
        }
        __syncthreads();
#pragma unroll
        for (int i = 0; i < 4; i++) {
            split_bf16(av[i].x, ahd + 4 * i + 0, ald + 4 * i + 0);
            split_bf16(av[i].y, ahd + 4 * i + 1, ald + 4 * i + 1);
            split_bf16(av[i].z, ahd + 4 * i + 2, ald + 4 * i + 2);
            split_bf16(av[i].w, ahd + 4 * i + 3, ald + 4 * i + 3);
            split_bf16(bv[i].x, bhd + 4 * i + 0, bld + 4 * i + 0);
            split_bf16(bv[i].y, bhd + 4 * i + 1, bld + 4 * i + 1);
            split_bf16(bv[i].z, bhd + 4 * i + 2, bld + 4 * i + 2);
            split_bf16(bv[i].w, bhd + 4 * i + 3, bld + 4 * i + 3);
        }
        __syncthreads();
        bf16x8 ah0 = *(const bf16x8*)(Ahi + arow * LSTRIDE + koff);
        bf16x8 ah1 = *(const bf16x8*)(Ahi + arow * LSTRIDE + 32 + koff);
        bf16x8 al0 = *(const bf16x8*)(Alo + arow * LSTRIDE + koff);
        bf16x8 al1 = *(const bf16x8*)(Alo + arow * LSTRIDE + 32 + koff);
#pragma unroll
        for (int tv = 0; tv < 4; tv++) {
            int brow = tv * 16 + (lane & 15);
            bf16x8 bh0 = *(const bf16x8*)(Bhi + brow * LSTRIDE + koff);
            bf16x8 bh1 = *(const bf16x8*)(Bhi + brow * LSTRIDE + 32 + koff);
            bf16x8 bl0 = *(const bf16x8*)(Blo + brow * LSTRIDE + koff);
            bf16x8 bl1 = *(const bf16x8*)(Blo + brow * LSTRIDE + 32 + koff);
            acc[tv] = __builtin_amdgcn_mfma_f32_16x16x32_bf16(ah0, bh0, acc[tv], 0, 0, 0);
            acc[tv] = __builtin_amdgcn_mfma_f32_16x16x32_bf16(ah1, bh1, acc[tv], 0, 0, 0);
            acc[tv] = __builtin_amdgcn_mfma_f32_16x16x32_bf16(al0, bh0, acc[tv], 0, 0, 0);
            acc[tv] = __builtin_amdgcn_mfma_f32_16x16x32_bf16(al1, bh1, acc[tv], 0, 0, 0);
            acc[tv] = __builtin_amdgcn_mfma_f32_16x16x32_bf16(ah0, bl0, acc[tv], 0, 0, 0);
            acc[tv] = __builtin_amdgcn_mfma_f32_16x16x32_bf16(ah1, bl1, acc[tv], 0, 0, 0);
        }
    }

    // epilogue: C/D layout col = lane&15 (v), row = (lane>>4)*4 + reg (b)
    int col = lane & 15;
    int quad = lane >> 4;
    unsigned long long kmax[4] = {0ull, 0ull, 0ull, 0ull};
#pragma unroll
    for (int tv = 0; tv < 4; tv++) {
        int v = vbase + tv * 16 + col;
        float bo = bout[v];
#pragma unroll
        for (int r = 0; r < 4; r++) {
            float lg = acc[tv][r] + bo;
            unsigned long long key = ((unsigned long long)ord_of_float(lg) << 32)
                                   | (unsigned long long)(0x7FFFFFFFu - (uint32_t)v);
            if (key > kmax[r]) kmax[r] = key;
        }
    }
#pragma unroll
    for (int r = 0; r < 4; r++) {
        unsigned long long k = kmax[r];
#pragma unroll
        for (int off = 1; off < 16; off <<= 1) {
            unsigned long long o = shfl_xor_u64(k, off);
            if (o > k) k = o;
        }
        kmax[r] = k;
    }
    if (col == 0) {
#pragma unroll
        for (int r = 0; r < 4; r++) {
            int b = wv * 16 + quad * 4 + r;
            partials[(size_t)b * nblk + blockIdx.x] = kmax[r];
        }
    }
}

// ---------------------------------------------------------------- token reduce
__global__ __launch_bounds__(64) void k_token(
    const unsigned long long* __restrict__ partials, int nblk,
    int* __restrict__ tok, float* __restrict__ out_tokens, int t)
{
    int b = blockIdx.x;
    int lane = threadIdx.x;
    unsigned long long k = 0ull;
    for (int i = lane; i < nblk; i += 64) {
        unsigned long long p = partials[(size_t)b * nblk + i];
        if (p > k) k = p;
    }
#pragma unroll
    for (int off = 32; off; off >>= 1) {
        unsigned long long o = shfl_xor_u64(k, off);
        if (o > k) k = o;
    }
    if (lane == 0) {
        int v = (int)(0x7FFFFFFFu - (uint32_t)(k & 0xFFFFFFFFull));
        tok[b] = v;
        out_tokens[b * T_ + t] = (float)v;
    }
}

// ---------------------------------------------------------------- final h copy
__global__ __launch_bounds__(256) void k_copy_h(const float* __restrict__ h,
                                               float* __restrict__ out)
{
    int i = (blockIdx.x * 256 + threadIdx.x) * 4;
    *(float4*)(out + i) = *(const float4*)(h + i);
}

// ---------------------------------------------------------------- launch
extern "C" void kernel_launch(void* const* d_in, const int* in_sizes, int n_in,
                              void* d_out, int out_size, void* d_ws, size_t ws_size,
                              hipStream_t stream)
{
    const float* latent = (const float*)d_in[0];
    const float* Wp     = (const float*)d_in[1];
    const float* bp     = (const float*)d_in[2];
    const float* emb    = (const float*)d_in[3];
    const float* Wih    = (const float*)d_in[4];
    const float* bih    = (const float*)d_in[5];
    const float* Whh    = (const float*)d_in[6];
    const float* bhh    = (const float*)d_in[7];
    const float* Wout   = (const float*)d_in[8];
    const float* bout   = (const float*)d_in[9];
    float* out = (float*)d_out;

    char* ws = (char*)d_ws;
    float* h0 = (float*)ws;                       // 256 KiB
    float* h1 = (float*)(ws + 262144);            // 256 KiB
    int* tok  = (int*)(ws + 524288);              // 256 B
    unsigned long long* partials = (unsigned long long*)(ws + 525312);  // 500*64*8
    const int NBLK = V_ / 64;                     // 500

    k_init_hidden<<<16384, 256, 0, stream>>>(latent, Wp, bp, h0);

    float* hp = h0;
    float* hn = h1;
    for (int t = 0; t < T_; t++) {
        k_gru_gates<<<H_ / 4, 256, 0, stream>>>(emb, tok, t == 0 ? 1 : 0,
                                                Wih, bih, Whh, bhh, hp, hn);
        k_logits_argmax<<<NBLK, 256, 0, stream>>>(hn, Wout, bout, partials, NBLK);
        k_token<<<B_, 64, 0, stream>>>(partials, NBLK, tok, out, t);
        float* tmp = hp; hp = hn; hn = tmp;
    }
    k_copy_h<<<64, 256, 0, stream>>>(hp, out + B_ * T_);
}

// Round 2
// 1417.550 us; speedup vs baseline: 2.1423x; 2.1423x over previous
//
#include <hip/hip_runtime.h>
#include <stdint.h>

#define B_ 64
#define D_ 1024
#define H_ 1024
#define V_ 32000
#define T_ 20

typedef __attribute__((ext_vector_type(8))) __bf16 bf16x8;
typedef __attribute__((ext_vector_type(4))) float f32x4;

// ---------------------------------------------------------------- helpers
__device__ __forceinline__ uint32_t ord_of_float(float x) {
    uint32_t u = __float_as_uint(x);
    return (u & 0x80000000u) ? ~u : (u | 0x80000000u);
}

__device__ __forceinline__ unsigned long long shfl_xor_u64(unsigned long long x, int m) {
    return (unsigned long long)__shfl_xor((long long)x, m, 64);
}

// round-to-nearest-even fp32 -> bf16 split: f ~= hi + lo (each bf16)
__device__ __forceinline__ void split_bf16(float f, unsigned short* hi, unsigned short* lo) {
    uint32_t u = __float_as_uint(f);
    uint32_t rh = (u + 0x7FFFu + ((u >> 16) & 1u)) >> 16;
    *hi = (unsigned short)rh;
    float fl = f - __uint_as_float(rh << 16);
    uint32_t ul = __float_as_uint(fl);
    uint32_t rl = (ul + 0x7FFFu + ((ul >> 16) & 1u)) >> 16;
    *lo = (unsigned short)rl;
}

// ---------------------------------------------------------------- init hidden
// h0[b][j] = dot(latent[b,:], Wp[j,:]) + bp[j].  One wave per output.
__global__ __launch_bounds__(256) void k_init_hidden(
    const float* __restrict__ latent, const float* __restrict__ Wp,
    const float* __restrict__ bp, float* __restrict__ h0)
{
    int gw = (blockIdx.x * 256 + threadIdx.x) >> 6;  // global wave id
    int lane = threadIdx.x & 63;
    int j = gw >> 6;      // 16 consecutive blocks share j -> L2 reuse of Wp row
    int b = gw & 63;
    const float4* a4 = (const float4*)(latent + b * D_);
    const float4* w4 = (const float4*)(Wp + (size_t)j * D_);
    float s = 0.f;
#pragma unroll
    for (int i = 0; i < 4; i++) {
        float4 a = a4[lane + 64 * i];
        float4 w = w4[lane + 64 * i];
        s += a.x * w.x + a.y * w.y + a.z * w.z + a.w * w.w;
    }
#pragma unroll
    for (int off = 32; off; off >>= 1) s += __shfl_down(s, off, 64);
    if (lane == 0) h0[b * H_ + j] = s + bp[j];
}

#define LSTRIDE 72  // 64 + 8 pad (keeps 16B alignment, 2-way-max conflicts)

// ---------------------------------------------------------------- gates GEMM (MFMA)
// Computes split-K partials of gi = x@Wih^T and gh = h@Whh^T with split-bf16
// 3-term MFMA (error ~1e-7).  Grid 192: jt(48) x half(2) x ks(2).
// Block tile: 64 b x 64 gate-cols x K=512.  Output gbuf[ks][half][64][3072] fp32.
__global__ __launch_bounds__(256) void k_gates_gemm(
    const float* __restrict__ emb, const int* __restrict__ tok, int use_sos,
    const float* __restrict__ hprev, const float* __restrict__ Wih,
    const float* __restrict__ Whh, float* __restrict__ gbuf)
{
    __shared__ unsigned short Ahi[64 * LSTRIDE], Alo[64 * LSTRIDE];
    __shared__ unsigned short Bhi[64 * LSTRIDE], Blo[64 * LSTRIDE];
    int tid = threadIdx.x;
    int lane = tid & 63;
    int wv = tid >> 6;
    int blk = blockIdx.x;
    int jt = blk % 48;
    int rest = blk / 48;        // 0..3
    int half = rest & 1;        // 0: ih (A=x), 1: hh (A=h)
    int ks = rest >> 1;         // split-K chunk
    int kbase = ks * 512;

    const float* W = half ? Whh : Wih;

    int srow = tid >> 2;        // staging row
    int scol = (tid & 3) * 16;  // staging col (16 floats per thread)
    const float* arow;
    if (half == 0) {
        int xr = use_sos ? 0 : tok[srow];
        arow = emb + (size_t)xr * H_;
    } else {
        arow = hprev + srow * H_;
    }
    const float* asrc = arow + kbase + scol;
    const float* bsrc = W + (size_t)(jt * 64 + srow) * H_ + kbase + scol;

    unsigned short* ahd = Ahi + srow * LSTRIDE + scol;
    unsigned short* ald = Alo + srow * LSTRIDE + scol;
    unsigned short* bhd = Bhi + srow * LSTRIDE + scol;
    unsigned short* bld = Blo + srow * LSTRIDE + scol;

    f32x4 acc[4];
#pragma unroll
    for (int i = 0; i < 4; i++) acc[i] = (f32x4){0.f, 0.f, 0.f, 0.f};

    int arow_f = wv * 16 + (lane & 15);
    int koff = (lane >> 4) * 8;

    for (int kc = 0; kc < 512; kc += 64) {
        float4 av[4], bv[4];
#pragma unroll
        for (int i = 0; i < 4; i++) {
            av[i] = *(const float4*)(asrc + kc + 4 * i);
            bv[i] = *(const float4*)(bsrc + kc + 4 * i);
        }
        __syncthreads();
#pragma unroll
        for (int i = 0; i < 4; i++) {
            split_bf16(av[i].x, ahd + 4 * i + 0, ald + 4 * i + 0);
            split_bf16(av[i].y, ahd + 4 * i + 1, ald + 4 * i + 1);
            split_bf16(av[i].z, ahd + 4 * i + 2, ald + 4 * i + 2);
            split_bf16(av[i].w, ahd + 4 * i + 3, ald + 4 * i + 3);
            split_bf16(bv[i].x, bhd + 4 * i + 0, bld + 4 * i + 0);
            split_bf16(bv[i].y, bhd + 4 * i + 1, bld + 4 * i + 1);
            split_bf16(bv[i].z, bhd + 4 * i + 2, bld + 4 * i + 2);
            split_bf16(bv[i].w, bhd + 4 * i + 3, bld + 4 * i + 3);
        }
        __syncthreads();
        bf16x8 ah0 = *(const bf16x8*)(Ahi + arow_f * LSTRIDE + koff);
        bf16x8 ah1 = *(const bf16x8*)(Ahi + arow_f * LSTRIDE + 32 + koff);
        bf16x8 al0 = *(const bf16x8*)(Alo + arow_f * LSTRIDE + koff);
        bf16x8 al1 = *(const bf16x8*)(Alo + arow_f * LSTRIDE + 32 + koff);
#pragma unroll
        for (int tv = 0; tv < 4; tv++) {
            int brow = tv * 16 + (lane & 15);
            bf16x8 bh0 = *(const bf16x8*)(Bhi + brow * LSTRIDE + koff);
            bf16x8 bh1 = *(const bf16x8*)(Bhi + brow * LSTRIDE + 32 + koff);
            bf16x8 bl0 = *(const bf16x8*)(Blo + brow * LSTRIDE + koff);
            bf16x8 bl1 = *(const bf16x8*)(Blo + brow * LSTRIDE + 32 + koff);
            acc[tv] = __builtin_amdgcn_mfma_f32_16x16x32_bf16(ah0, bh0, acc[tv], 0, 0, 0);
            acc[tv] = __builtin_amdgcn_mfma_f32_16x16x32_bf16(ah1, bh1, acc[tv], 0, 0, 0);
            acc[tv] = __builtin_amdgcn_mfma_f32_16x16x32_bf16(al0, bh0, acc[tv], 0, 0, 0);
            acc[tv] = __builtin_amdgcn_mfma_f32_16x16x32_bf16(al1, bh1, acc[tv], 0, 0, 0);
            acc[tv] = __builtin_amdgcn_mfma_f32_16x16x32_bf16(ah0, bl0, acc[tv], 0, 0, 0);
            acc[tv] = __builtin_amdgcn_mfma_f32_16x16x32_bf16(ah1, bl1, acc[tv], 0, 0, 0);
        }
    }

    // epilogue: C/D layout col = lane&15 (n), row = (lane>>4)*4 + reg (b)
    int col = lane & 15;
    int quad = lane >> 4;
    float* og = gbuf + (size_t)((ks * 2 + half) * 64) * 3072;
#pragma unroll
    for (int tv = 0; tv < 4; tv++) {
#pragma unroll
        for (int r = 0; r < 4; r++) {
            int b = wv * 16 + quad * 4 + r;
            og[(size_t)b * 3072 + jt * 64 + tv * 16 + col] = acc[tv][r];
        }
    }
}

// ---------------------------------------------------------------- gate elementwise
__global__ __launch_bounds__(256) void k_gru_elem(
    const float* __restrict__ gbuf, const float* __restrict__ bih,
    const float* __restrict__ bhh, const float* __restrict__ hprev,
    float* __restrict__ hnext)
{
    int idx = blockIdx.x * 256 + threadIdx.x;   // 0..65535
    int b = idx >> 10;
    int j = idx & 1023;
    const float* g00 = gbuf + (size_t)b * 3072;            // ks0, ih
    const float* g01 = gbuf + (size_t)(64 + b) * 3072;     // ks0, hh
    const float* g10 = gbuf + (size_t)(128 + b) * 3072;    // ks1, ih
    const float* g11 = gbuf + (size_t)(192 + b) * 3072;    // ks1, hh
    float ir = g00[j] + g10[j] + bih[j];
    float hr = g01[j] + g11[j] + bhh[j];
    float iz = g00[H_ + j] + g10[H_ + j] + bih[H_ + j];
    float hz = g01[H_ + j] + g11[H_ + j] + bhh[H_ + j];
    float in_ = g00[2 * H_ + j] + g10[2 * H_ + j] + bih[2 * H_ + j];
    float hn = g01[2 * H_ + j] + g11[2 * H_ + j] + bhh[2 * H_ + j];
    float r = 1.f / (1.f + expf(-(ir + hr)));
    float z = 1.f / (1.f + expf(-(iz + hz)));
    float n = tanhf(in_ + r * hn);
    float hp = hprev[idx];
    hnext[idx] = (1.f - z) * n + z * hp;
}

// ---------------------------------------------------------------- logits + argmax
// Split-precision bf16 MFMA GEMM: logits = h @ Wout^T + bout.  Block: 64 b x 64 v.
__global__ __launch_bounds__(256) void k_logits_argmax(
    const float* __restrict__ hcur, const float* __restrict__ Wout,
    const float* __restrict__ bout, unsigned long long* __restrict__ partials,
    int nblk)
{
    __shared__ unsigned short Ahi[64 * LSTRIDE], Alo[64 * LSTRIDE];
    __shared__ unsigned short Bhi[64 * LSTRIDE], Blo[64 * LSTRIDE];
    int tid = threadIdx.x;
    int lane = tid & 63;
    int wv = tid >> 6;
    int vbase = blockIdx.x * 64;

    int srow = tid >> 2;
    int scol = (tid & 3) * 16;
    const float* asrc = hcur + srow * H_ + scol;
    const float* bsrc = Wout + (size_t)(vbase + srow) * H_ + scol;
    unsigned short* ahd = Ahi + srow * LSTRIDE + scol;
    unsigned short* ald = Alo + srow * LSTRIDE + scol;
    unsigned short* bhd = Bhi + srow * LSTRIDE + scol;
    unsigned short* bld = Blo + srow * LSTRIDE + scol;

    f32x4 acc[4];
#pragma unroll
    for (int i = 0; i < 4; i++) acc[i] = (f32x4){0.f, 0.f, 0.f, 0.f};

    int arow = wv * 16 + (lane & 15);
    int koff = (lane >> 4) * 8;

    for (int kc = 0; kc < H_; kc += 64) {
        float4 av[4], bv[4];
#pragma unroll
        for (int i = 0; i < 4; i++) {
            av[i] = *(const float4*)(asrc + kc + 4 * i);
            bv[i] = *(const float4*)(bsrc + kc + 4 * i);
        }
        __syncthreads();
#pragma unroll
        for (int i = 0; i < 4; i++) {
            split_bf16(av[i].x, ahd + 4 * i + 0, ald + 4 * i + 0);
            split_bf16(av[i].y, ahd + 4 * i + 1, ald + 4 * i + 1);
            split_bf16(av[i].z, ahd + 4 * i + 2, ald + 4 * i + 2);
            split_bf16(av[i].w, ahd + 4 * i + 3, ald + 4 * i + 3);
            split_bf16(bv[i].x, bhd + 4 * i + 0, bld + 4 * i + 0);
            split_bf16(bv[i].y, bhd + 4 * i + 1, bld + 4 * i + 1);
            split_bf16(bv[i].z, bhd + 4 * i + 2, bld + 4 * i + 2);
            split_bf16(bv[i].w, bhd + 4 * i + 3, bld + 4 * i + 3);
        }
        __syncthreads();
        bf16x8 ah0 = *(const bf16x8*)(Ahi + arow * LSTRIDE + koff);
        bf16x8 ah1 = *(const bf16x8*)(Ahi + arow * LSTRIDE + 32 + koff);
        bf16x8 al0 = *(const bf16x8*)(Alo + arow * LSTRIDE + koff);
        bf16x8 al1 = *(const bf16x8*)(Alo + arow * LSTRIDE + 32 + koff);
#pragma unroll
        for (int tv = 0; tv < 4; tv++) {
            int brow = tv * 16 + (lane & 15);
            bf16x8 bh0 = *(const bf16x8*)(Bhi + brow * LSTRIDE + koff);
            bf16x8 bh1 = *(const bf16x8*)(Bhi + brow * LSTRIDE + 32 + koff);
            bf16x8 bl0 = *(const bf16x8*)(Blo + brow * LSTRIDE + koff);
            bf16x8 bl1 = *(const bf16x8*)(Blo + brow * LSTRIDE + 32 + koff);
            acc[tv] = __builtin_amdgcn_mfma_f32_16x16x32_bf16(ah0, bh0, acc[tv], 0, 0, 0);
            acc[tv] = __builtin_amdgcn_mfma_f32_16x16x32_bf16(ah1, bh1, acc[tv], 0, 0, 0);
            acc[tv] = __builtin_amdgcn_mfma_f32_16x16x32_bf16(al0, bh0, acc[tv], 0, 0, 0);
            acc[tv] = __builtin_amdgcn_mfma_f32_16x16x32_bf16(al1, bh1, acc[tv], 0, 0, 0);
            acc[tv] = __builtin_amdgcn_mfma_f32_16x16x32_bf16(ah0, bl0, acc[tv], 0, 0, 0);
            acc[tv] = __builtin_amdgcn_mfma_f32_16x16x32_bf16(ah1, bl1, acc[tv], 0, 0, 0);
        }
    }

    // epilogue: C/D layout col = lane&15 (v), row = (lane>>4)*4 + reg (b)
    int col = lane & 15;
    int quad = lane >> 4;
    unsigned long long kmax[4] = {0ull, 0ull, 0ull, 0ull};
#pragma unroll
    for (int tv = 0; tv < 4; tv++) {
        int v = vbase + tv * 16 + col;
        float bo = bout[v];
#pragma unroll
        for (int r = 0; r < 4; r++) {
            float lg = acc[tv][r] + bo;
            unsigned long long key = ((unsigned long long)ord_of_float(lg) << 32)
                                   | (unsigned long long)(0x7FFFFFFFu - (uint32_t)v);
            if (key > kmax[r]) kmax[r] = key;
        }
    }
#pragma unroll
    for (int r = 0; r < 4; r++) {
        unsigned long long k = kmax[r];
#pragma unroll
        for (int off = 1; off < 16; off <<= 1) {
            unsigned long long o = shfl_xor_u64(k, off);
            if (o > k) k = o;
        }
        kmax[r] = k;
    }
    if (col == 0) {
#pragma unroll
        for (int r = 0; r < 4; r++) {
            int b = wv * 16 + quad * 4 + r;
            partials[(size_t)b * nblk + blockIdx.x] = kmax[r];
        }
    }
}

// ---------------------------------------------------------------- token reduce
__global__ __launch_bounds__(64) void k_token(
    const unsigned long long* __restrict__ partials, int nblk,
    int* __restrict__ tok, float* __restrict__ out_tokens, int t)
{
    int b = blockIdx.x;
    int lane = threadIdx.x;
    unsigned long long k = 0ull;
    for (int i = lane; i < nblk; i += 64) {
        unsigned long long p = partials[(size_t)b * nblk + i];
        if (p > k) k = p;
    }
#pragma unroll
    for (int off = 32; off; off >>= 1) {
        unsigned long long o = shfl_xor_u64(k, off);
        if (o > k) k = o;
    }
    if (lane == 0) {
        int v = (int)(0x7FFFFFFFu - (uint32_t)(k & 0xFFFFFFFFull));
        tok[b] = v;
        out_tokens[b * T_ + t] = (float)v;
    }
}

// ---------------------------------------------------------------- final h copy
__global__ __launch_bounds__(256) void k_copy_h(const float* __restrict__ h,
                                               float* __restrict__ out)
{
    int i = (blockIdx.x * 256 + threadIdx.x) * 4;
    *(float4*)(out + i) = *(const float4*)(h + i);
}

// ---------------------------------------------------------------- launch
extern "C" void kernel_launch(void* const* d_in, const int* in_sizes, int n_in,
                              void* d_out, int out_size, void* d_ws, size_t ws_size,
                              hipStream_t stream)
{
    const float* latent = (const float*)d_in[0];
    const float* Wp     = (const float*)d_in[1];
    const float* bp     = (const float*)d_in[2];
    const float* emb    = (const float*)d_in[3];
    const float* Wih    = (const float*)d_in[4];
    const float* bih    = (const float*)d_in[5];
    const float* Whh    = (const float*)d_in[6];
    const float* bhh    = (const float*)d_in[7];
    const float* Wout   = (const float*)d_in[8];
    const float* bout   = (const float*)d_in[9];
    float* out = (float*)d_out;

    char* ws = (char*)d_ws;
    float* h0 = (float*)ws;                       // 256 KiB
    float* h1 = (float*)(ws + 262144);            // 256 KiB
    int* tok  = (int*)(ws + 524288);              // 256 B
    unsigned long long* partials = (unsigned long long*)(ws + 525312);  // 500*64*8
    float* gbuf = (float*)(ws + 786432);          // 4*64*3072*4 = 3 MiB
    const int NBLK = V_ / 64;                     // 500

    k_init_hidden<<<16384, 256, 0, stream>>>(latent, Wp, bp, h0);

    float* hp = h0;
    float* hn = h1;
    for (int t = 0; t < T_; t++) {
        k_gates_gemm<<<192, 256, 0, stream>>>(emb, tok, t == 0 ? 1 : 0,
                                              hp, Wih, Whh, gbuf);
        k_gru_elem<<<256, 256, 0, stream>>>(gbuf, bih, bhh, hp, hn);
        k_logits_argmax<<<NBLK, 256, 0, stream>>>(hn, Wout, bout, partials, NBLK);
        k_token<<<B_, 64, 0, stream>>>(partials, NBLK, tok, out, t);
        float* tmp = hp; hp = hn; hn = tmp;
    }
    k_copy_h<<<64, 256, 0, stream>>>(hp, out + B_ * T_);
}